// Round 2
// baseline (86.579 us; speedup 1.0000x reference)
//
#include <hip/hip_runtime.h>

typedef float vf4 __attribute__((ext_vector_type(4)));

#define TWO_PI_F 6.283185307179586f
#define L2T_OVER_64 0.20762050594f  /* log2(10000)/64 */

// Kernel 1: per-batch exclusive offset (sum of num_nodes[0..b-1]) and
// per-batch coordinate maxima -> store 2pi/(max+eps). Shuffle reductions,
// only 2 barriers.
__global__ void prep_kernel(const float* __restrict__ centroid,
                            const int* __restrict__ num_nodes,
                            int B, int N,
                            int* __restrict__ offsets,
                            float* __restrict__ inv_x,
                            float* __restrict__ inv_y) {
    __shared__ int s_i[4];
    __shared__ float s_x[4], s_y[4];
    const int b = blockIdx.x;
    const int t = threadIdx.x;
    const int wave = t >> 6, lane = t & 63;

    int v = (t < b) ? num_nodes[t] : 0;   // b < B and t<b implies t<B
    for (int d = 1; d < 64; d <<= 1) v += __shfl_xor(v, d);
    if (lane == 0) s_i[wave] = v;
    __syncthreads();
    const int offset = s_i[0] + s_i[1] + s_i[2] + s_i[3];

    const int nn = num_nodes[b];
    const int n_eff = min(nn, N);
    float mx = 0.0f, my = 0.0f;   // padded zeros participate; coords >= 0
    for (int j = t; j < n_eff; j += 256) {
        float2 c = ((const float2*)centroid)[offset + j];
        mx = fmaxf(mx, c.x);
        my = fmaxf(my, c.y);
    }
    for (int d = 1; d < 64; d <<= 1) {
        mx = fmaxf(mx, __shfl_xor(mx, d));
        my = fmaxf(my, __shfl_xor(my, d));
    }
    if (lane == 0) { s_x[wave] = mx; s_y[wave] = my; }
    __syncthreads();
    if (t == 0) {
        mx = fmaxf(fmaxf(s_x[0], s_x[1]), fmaxf(s_x[2], s_x[3]));
        my = fmaxf(fmaxf(s_y[0], s_y[1]), fmaxf(s_y[2], s_y[3]));
        offsets[b] = offset;
        inv_x[b] = TWO_PI_F / (mx + 1e-6f);
        inv_y[b] = TWO_PI_F / (my + 1e-6f);
    }
}

// Kernel 2: one 64-lane group per output row; persistent blocks with a
// 2-deep software pipeline (load row i+stride while storing row i).
__global__ __launch_bounds__(256) void main_kernel(
    const float* __restrict__ patch,
    const float* __restrict__ centroid,
    const int* __restrict__ num_nodes,
    const int* __restrict__ offsets,
    const float* __restrict__ inv_x,
    const float* __restrict__ inv_y,
    int N, int nshift, int rows,
    float* __restrict__ out_feat,
    float* __restrict__ out_mask,
    float* __restrict__ out_emb) {
    const int tid = threadIdx.x;
    const int lane = tid & 63;
    const int stride = gridDim.x * 4;
    int row = blockIdx.x * 4 + (tid >> 6);
    if (row >= rows) return;

    const int m = lane & 31;  // this lane covers emb elements 4m..4m+3 of its half
    const float inv0 = exp2f(-(float)(2 * m) * L2T_OVER_64);
    const float inv1 = exp2f(-(float)(2 * m + 1) * L2T_OVER_64);

    auto load_row = [&](int rw, vf4& f_, float& x_, float& y_,
                        float& ivx_, float& ivy_, int& nn_, int& j_) {
        int b = (nshift >= 0) ? (rw >> nshift) : (rw / N);
        j_ = rw - b * N;
        nn_ = num_nodes[b];
        ivx_ = inv_x[b];
        ivy_ = inv_y[b];
        f_ = (vf4)(0.0f);
        x_ = 0.0f; y_ = 0.0f;
        if (j_ < min(nn_, N)) {
            int src = offsets[b] + j_;
            const vf4* pf = (const vf4*)(patch + (size_t)src * 256);
            f_ = __builtin_nontemporal_load(pf + lane);
            float2 c = ((const float2*)centroid)[src];
            x_ = c.x; y_ = c.y;
        }
    };

    auto store_row = [&](int rw, vf4 f_, float x_, float y_,
                         float ivx_, float ivy_, int nn_, int j_) {
        vf4* of = (vf4*)(out_feat + (size_t)rw * 256);
        __builtin_nontemporal_store(f_, of + lane);
        if (lane == 0)
            out_mask[rw] = (j_ >= nn_ + 1) ? 1.0f : 0.0f;
        const float a = (lane < 32) ? (y_ * ivy_) : (x_ * ivx_);
        float s0, c0, s1, c1;
        __sincosf(a * inv0, &s0, &c0);
        __sincosf(a * inv1, &s1, &c1);
        vf4 e = {s0, c0, s1, c1};
        vf4* oe = (vf4*)(out_emb + (size_t)rw * 256);
        __builtin_nontemporal_store(e, oe + lane);
    };

    vf4 f; float x, y, ivx, ivy; int nn, j;
    load_row(row, f, x, y, ivx, ivy, nn, j);
    int nrow = row + stride;
    while (nrow < rows) {
        vf4 f2; float x2, y2, ivx2, ivy2; int nn2, j2;
        load_row(nrow, f2, x2, y2, ivx2, ivy2, nn2, j2);
        store_row(row, f, x, y, ivx, ivy, nn, j);
        row = nrow; f = f2; x = x2; y = y2;
        ivx = ivx2; ivy = ivy2; nn = nn2; j = j2;
        nrow = row + stride;
    }
    store_row(row, f, x, y, ivx, ivy, nn, j);
}

extern "C" void kernel_launch(void* const* d_in, const int* in_sizes, int n_in,
                              void* d_out, int out_size, void* d_ws, size_t ws_size,
                              hipStream_t stream) {
    (void)n_in; (void)ws_size;
    const float* patch     = (const float*)d_in[0];
    const float* centroid  = (const float*)d_in[1];
    const int*   num_nodes = (const int*)d_in[2];

    const int B = in_sizes[2];                 // 256
    const int C = 256;                         // feature dim (fixed by problem)
    const int N = out_size / (B * (C + 257));  // 512

    int nshift = -1;
    if ((N & (N - 1)) == 0) {                  // pow2 -> shift instead of div
        int s = 0, v = N;
        while (v > 1) { v >>= 1; ++s; }
        nshift = s;
    }

    float* out_feat = (float*)d_out;
    float* out_mask = out_feat + (size_t)B * N * C;
    float* out_emb  = out_mask + (size_t)B * N;

    int*   offsets = (int*)d_ws;
    float* inv_x   = (float*)d_ws + B;
    float* inv_y   = inv_x + B;

    prep_kernel<<<B, 256, 0, stream>>>(centroid, num_nodes, B, N, offsets, inv_x, inv_y);

    const int rows = B * N;
    int blocks = (rows + 3) / 4;
    if (blocks > 2048) blocks = 2048;          // persistent: ~8 blocks/CU
    main_kernel<<<blocks, 256, 0, stream>>>(
        patch, centroid, num_nodes, offsets, inv_x, inv_y,
        N, nshift, rows, out_feat, out_mask, out_emb);
}

// Round 3
// 78.105 us; speedup vs baseline: 1.1085x; 1.1085x over previous
//
#include <hip/hip_runtime.h>

typedef float vf4 __attribute__((ext_vector_type(4)));

#define TWO_PI_F 6.283185307179586f
#define L2T_OVER_64 0.20762050594f  /* log2(10000)/64 */

// Kernel 0: per-batch exclusive offset (sum of num_nodes[0..b-1]) and
// per-batch coordinate maxima -> store 2pi/(max+eps).
__global__ void prep_kernel(const float* __restrict__ centroid,
                            const int* __restrict__ num_nodes,
                            int B, int N,
                            int* __restrict__ offsets,
                            float* __restrict__ inv_x,
                            float* __restrict__ inv_y) {
    __shared__ int s_i[4];
    __shared__ float s_x[4], s_y[4];
    const int b = blockIdx.x;
    const int t = threadIdx.x;
    const int wave = t >> 6, lane = t & 63;

    int v = (t < b) ? num_nodes[t] : 0;   // t < b <= B-1 implies t < B
    for (int d = 1; d < 64; d <<= 1) v += __shfl_xor(v, d);
    if (lane == 0) s_i[wave] = v;
    __syncthreads();
    const int offset = s_i[0] + s_i[1] + s_i[2] + s_i[3];

    const int nn = num_nodes[b];
    const int n_eff = min(nn, N);
    float mx = 0.0f, my = 0.0f;   // padded zeros participate; coords >= 0
    for (int j = t; j < n_eff; j += 256) {
        float2 c = ((const float2*)centroid)[offset + j];
        mx = fmaxf(mx, c.x);
        my = fmaxf(my, c.y);
    }
    for (int d = 1; d < 64; d <<= 1) {
        mx = fmaxf(mx, __shfl_xor(mx, d));
        my = fmaxf(my, __shfl_xor(my, d));
    }
    if (lane == 0) { s_x[wave] = mx; s_y[wave] = my; }
    __syncthreads();
    if (t == 0) {
        mx = fmaxf(fmaxf(s_x[0], s_x[1]), fmaxf(s_x[2], s_x[3]));
        my = fmaxf(fmaxf(s_y[0], s_y[1]), fmaxf(s_y[2], s_y[3]));
        offsets[b] = offset;
        inv_x[b] = TWO_PI_F / (mx + 1e-6f);
        inv_y[b] = TWO_PI_F / (my + 1e-6f);
    }
}

// Kernel A: feature gather-copy. 2 rows per wave (2 KB contiguous read,
// 2 KB contiguous write, 2 loads in flight). 1 read + 1 write stream.
__global__ __launch_bounds__(256) void feat_kernel(
    const float* __restrict__ patch,
    const int* __restrict__ num_nodes,
    const int* __restrict__ offsets,
    int N, int nshift, int rows,
    float* __restrict__ out_feat) {
    const int tid = threadIdx.x;
    const int lane = tid & 63;
    const int row0 = blockIdx.x * 8 + (tid >> 6) * 2;
    const int row1 = row0 + 1;
    if (row0 >= rows) return;

    const int b0 = (nshift >= 0) ? (row0 >> nshift) : (row0 / N);
    const int j0 = row0 - b0 * N;
    vf4 f0 = (vf4)(0.0f), f1 = (vf4)(0.0f);
    const int nn0 = num_nodes[b0];
    if (j0 < min(nn0, N))
        f0 = ((const vf4*)(patch + (size_t)(offsets[b0] + j0) * 256))[lane];

    bool w1 = (row1 < rows);
    if (w1) {
        const int b1 = (nshift >= 0) ? (row1 >> nshift) : (row1 / N);
        const int j1 = row1 - b1 * N;
        const int nn1 = num_nodes[b1];
        if (j1 < min(nn1, N))
            f1 = ((const vf4*)(patch + (size_t)(offsets[b1] + j1) * 256))[lane];
    }
    ((vf4*)(out_feat + (size_t)row0 * 256))[lane] = f0;
    if (w1)
        ((vf4*)(out_feat + (size_t)row1 * 256))[lane] = f1;
}

// Kernel B: sine positional embedding + mask. Compute + 1 big write stream
// (centroid/meta reads are L2-resident). 2 rows per wave.
__global__ __launch_bounds__(256) void emb_kernel(
    const float* __restrict__ centroid,
    const int* __restrict__ num_nodes,
    const int* __restrict__ offsets,
    const float* __restrict__ inv_x,
    const float* __restrict__ inv_y,
    int N, int nshift, int rows,
    float* __restrict__ out_mask,
    float* __restrict__ out_emb) {
    const int tid = threadIdx.x;
    const int lane = tid & 63;
    const int row0 = blockIdx.x * 8 + (tid >> 6) * 2;
    if (row0 >= rows) return;

    const int m = lane & 31;  // covers emb elements 4m..4m+3 of this half
    const float inv0 = exp2f(-(float)(2 * m) * L2T_OVER_64);
    const float inv1 = exp2f(-(float)(2 * m + 1) * L2T_OVER_64);

    #pragma unroll
    for (int r = 0; r < 2; ++r) {
        const int row = row0 + r;
        if (row >= rows) break;
        const int b = (nshift >= 0) ? (row >> nshift) : (row / N);
        const int j = row - b * N;
        const int nn = num_nodes[b];
        float x = 0.0f, y = 0.0f;
        if (j < min(nn, N)) {
            float2 c = ((const float2*)centroid)[offsets[b] + j];
            x = c.x; y = c.y;
        }
        if (lane == 0)
            out_mask[row] = (j >= nn + 1) ? 1.0f : 0.0f;
        const float a = (lane < 32) ? (y * inv_y[b]) : (x * inv_x[b]);
        float s0, c0, s1, c1;
        __sincosf(a * inv0, &s0, &c0);
        __sincosf(a * inv1, &s1, &c1);
        vf4 e = {s0, c0, s1, c1};
        ((vf4*)(out_emb + (size_t)row * 256))[lane] = e;
    }
}

extern "C" void kernel_launch(void* const* d_in, const int* in_sizes, int n_in,
                              void* d_out, int out_size, void* d_ws, size_t ws_size,
                              hipStream_t stream) {
    (void)n_in; (void)ws_size;
    const float* patch     = (const float*)d_in[0];
    const float* centroid  = (const float*)d_in[1];
    const int*   num_nodes = (const int*)d_in[2];

    const int B = in_sizes[2];                 // 256
    const int C = 256;                         // feature dim (fixed by problem)
    const int N = out_size / (B * (C + 257));  // 512

    int nshift = -1;
    if ((N & (N - 1)) == 0) {                  // pow2 -> shift instead of div
        int s = 0, v = N;
        while (v > 1) { v >>= 1; ++s; }
        nshift = s;
    }

    float* out_feat = (float*)d_out;
    float* out_mask = out_feat + (size_t)B * N * C;
    float* out_emb  = out_mask + (size_t)B * N;

    int*   offsets = (int*)d_ws;
    float* inv_x   = (float*)d_ws + B;
    float* inv_y   = inv_x + B;

    prep_kernel<<<B, 256, 0, stream>>>(centroid, num_nodes, B, N, offsets, inv_x, inv_y);

    const int rows = B * N;
    const int blocks = (rows + 7) / 8;
    feat_kernel<<<blocks, 256, 0, stream>>>(
        patch, num_nodes, offsets, N, nshift, rows, out_feat);
    emb_kernel<<<blocks, 256, 0, stream>>>(
        centroid, num_nodes, offsets, inv_x, inv_y,
        N, nshift, rows, out_mask, out_emb);
}

// Round 5
// 71.038 us; speedup vs baseline: 1.2188x; 1.0995x over previous
//
#include <hip/hip_runtime.h>

typedef float vf4 __attribute__((ext_vector_type(4)));

#define TWO_PI_F 6.283185307179586f
#define L2T_OVER_64 0.20762050594f  /* log2(10000)/64 */

// Single fused dispatch. Blocks come in pairs: even blockIdx -> feature
// gather-copy for an 8-row slab; odd blockIdx -> pos-embedding + mask for the
// same slab. N % 8 == 0 so every slab lives in ONE batch; each block
// recomputes its batch's exclusive offset (1 KB L1-hot scan of num_nodes) and,
// for emb blocks, the per-batch coordinate maxima (<=4 KB L2-hot centroid
// scan). No prep kernel, no workspace, no inter-kernel dependencies.
__global__ __launch_bounds__(256) void fused_kernel(
    const float* __restrict__ patch,
    const float* __restrict__ centroid,
    const int* __restrict__ num_nodes,
    int N, int nshift,
    float* __restrict__ out_feat,
    float* __restrict__ out_mask,
    float* __restrict__ out_emb) {
    const int tid = threadIdx.x;
    const int lane = tid & 63;
    const int wave = tid >> 6;
    const int role = blockIdx.x & 1;
    const int slab = blockIdx.x >> 1;
    const int row_base = slab * 8;
    const int b = (nshift >= 0) ? (row_base >> nshift) : (row_base / N);
    const int jbase = row_base - b * N;

    __shared__ int s_i[4];
    __shared__ float s_x[4], s_y[4];

    // exclusive offset: sum num_nodes[0..b-1]
    int v = 0;
    for (int t0 = tid; t0 < b; t0 += 256) v += num_nodes[t0];
    for (int d = 1; d < 64; d <<= 1) v += __shfl_xor(v, d);
    if (lane == 0) s_i[wave] = v;
    __syncthreads();
    const int offset = s_i[0] + s_i[1] + s_i[2] + s_i[3];
    const int nn = num_nodes[b];
    const int n_eff = min(nn, N);

    if (role == 0) {
        // ---- features: 2 adjacent rows per wave (2 KB read, 2 KB write) ----
        const int j0 = jbase + wave * 2;
        vf4 f0 = (vf4)(0.0f), f1 = (vf4)(0.0f);
        if (j0 < n_eff)
            f0 = ((const vf4*)(patch + (size_t)(offset + j0) * 256))[lane];
        if (j0 + 1 < n_eff)
            f1 = ((const vf4*)(patch + (size_t)(offset + j0 + 1) * 256))[lane];
        const int row0 = row_base + wave * 2;
        ((vf4*)(out_feat + (size_t)row0 * 256))[lane] = f0;
        ((vf4*)(out_feat + (size_t)(row0 + 1) * 256))[lane] = f1;
    } else {
        // ---- mask + sine embedding ----
        // per-batch maxima -> 2pi/(max+eps)
        float mx = 0.0f, my = 0.0f;   // zeros participate; coords >= 0
        for (int j = tid; j < n_eff; j += 256) {
            float2 c = ((const float2*)centroid)[offset + j];
            mx = fmaxf(mx, c.x);
            my = fmaxf(my, c.y);
        }
        for (int d = 1; d < 64; d <<= 1) {
            mx = fmaxf(mx, __shfl_xor(mx, d));
            my = fmaxf(my, __shfl_xor(my, d));
        }
        if (lane == 0) { s_x[wave] = mx; s_y[wave] = my; }
        __syncthreads();
        mx = fmaxf(fmaxf(s_x[0], s_x[1]), fmaxf(s_x[2], s_x[3]));
        my = fmaxf(fmaxf(s_y[0], s_y[1]), fmaxf(s_y[2], s_y[3]));
        const float ivx = TWO_PI_F / (mx + 1e-6f);
        const float ivy = TWO_PI_F / (my + 1e-6f);

        if (tid < 8)   // 8 mask values, one 32 B contiguous write
            out_mask[row_base + tid] = (jbase + tid >= nn + 1) ? 1.0f : 0.0f;

        const int m = lane & 31;  // emb elements 4m..4m+3 of this half
        const float inv0 = exp2f(-(float)(2 * m) * L2T_OVER_64);
        const float inv1 = exp2f(-(float)(2 * m + 1) * L2T_OVER_64);

        #pragma unroll
        for (int r = 0; r < 2; ++r) {
            const int j = jbase + wave * 2 + r;
            float x = 0.0f, y = 0.0f;
            if (j < n_eff) {
                float2 c = ((const float2*)centroid)[offset + j];
                x = c.x; y = c.y;
            }
            const float a = (lane < 32) ? (y * ivy) : (x * ivx);
            float s0, c0, s1, c1;
            __sincosf(a * inv0, &s0, &c0);
            __sincosf(a * inv1, &s1, &c1);
            vf4 e = {s0, c0, s1, c1};
            ((vf4*)(out_emb + (size_t)(row_base + wave * 2 + r) * 256))[lane] = e;
        }
    }
}

extern "C" void kernel_launch(void* const* d_in, const int* in_sizes, int n_in,
                              void* d_out, int out_size, void* d_ws, size_t ws_size,
                              hipStream_t stream) {
    (void)n_in; (void)d_ws; (void)ws_size;
    const float* patch     = (const float*)d_in[0];
    const float* centroid  = (const float*)d_in[1];
    const int*   num_nodes = (const int*)d_in[2];

    const int B = in_sizes[2];                 // 256
    const int C = 256;                         // feature dim (fixed by problem)
    const int N = out_size / (B * (C + 257));  // 512

    int nshift = -1;
    if ((N & (N - 1)) == 0) {                  // pow2 -> shift instead of div
        int s = 0, v = N;
        while (v > 1) { v >>= 1; ++s; }
        nshift = s;
    }

    float* out_feat = (float*)d_out;
    float* out_mask = out_feat + (size_t)B * N * C;
    float* out_emb  = out_mask + (size_t)B * N;

    const int rows = B * N;                    // divisible by 8 (N % 8 == 0)
    const int slabs = rows / 8;
    fused_kernel<<<slabs * 2, 256, 0, stream>>>(
        patch, centroid, num_nodes, N, nshift, out_feat, out_mask, out_emb);
}